// Round 2
// baseline (1212.304 us; speedup 1.0000x reference)
//
#include <hip/hip_runtime.h>
#include <hip/hip_bf16.h>
#include <stdint.h>

typedef unsigned short ushortT;

#define MM 1024
#define NN 4096
#define DD 128
#define EPSX 0.05f
#define STRENGTH 0.5f
#define TINYX 1e-12f
#define NITER 50

// ---- old layout (prologue + f32 fallback path) ----
#define WS_MAXCOST 0
#define WS_MAXCAP  1
#define WS_KSUM_SLOTS 16   // 64 slots
#define WS_SCORE_SLOTS 80  // 64 slots (fallback)
#define WS_T_SLOTS 144     // 2 x 64 slots (fallback)
#define WS_U 512           // u2 (k_norms/k_cost), then fallback u
#define WS_V 1536          // v2 (k_norms/k_cost), then fallback v
#define K_BYTE_OFF 32768
#define FAST_NEED (32768ull + 2ull * 8388608ull)

// ---- new layout for cooperative fast path (float/u32 indices into ws) ----
#define WSN_U  2048        // 1024 floats (live after v2 is dead)
#define WSN_V  3072        // 4096 floats
#define WSN_T  7168        // 2 x 256 per-WG t slots
#define WSN_SC 7680        // 256 per-WG score slots
#define BAR_SUB    7936    // 8 sub-counters, stride 16 u32
#define BAR_MASTER 8064
#define BAR_GEN    8096    // 8 gen copies, stride 8 u32
#define NWG 256
#define NTHR 512

__device__ inline float bf2f(ushortT u) { return __uint_as_float(((unsigned)u) << 16); }
__device__ inline ushortT f2bf(float f) {
    unsigned b = __float_as_uint(f);
    b += 0x7fffu + ((b >> 16) & 1u);
    return (ushortT)(b >> 16);
}
__device__ inline float wave_sum(float v) {
    for (int o = 32; o; o >>= 1) v += __shfl_down(v, o);
    return v;
}
__device__ inline float wave_max(float v) {
    for (int o = 32; o; o >>= 1) v = fmaxf(v, __shfl_down(v, o));
    return v;
}

// hierarchical monotonic grid barrier (cooperative launch guarantees co-residency)
__device__ inline void grid_bar(unsigned* w, unsigned target) {
    __syncthreads();
    if (threadIdx.x == 0) {
        __threadfence();  // publish this WG's global writes device-wide
        int sg = blockIdx.x & 7;
        unsigned prev = __hip_atomic_fetch_add(&w[BAR_SUB + sg * 16], 1u,
                                               __ATOMIC_RELAXED, __HIP_MEMORY_SCOPE_AGENT);
        if (prev + 1u == target * (NWG / 8)) {  // last of subgroup this round
            unsigned pm = __hip_atomic_fetch_add(&w[BAR_MASTER], 1u,
                                                 __ATOMIC_RELAXED, __HIP_MEMORY_SCOPE_AGENT);
            if (pm + 1u == target * 8u) {  // last subgroup overall
#pragma unroll
                for (int x = 0; x < 8; ++x)
                    __hip_atomic_store(&w[BAR_GEN + x * 8], target,
                                       __ATOMIC_RELAXED, __HIP_MEMORY_SCOPE_AGENT);
            }
        }
        while (__hip_atomic_load(&w[BAR_GEN + sg * 8], __ATOMIC_RELAXED,
                                 __HIP_MEMORY_SCOPE_AGENT) < target)
            __builtin_amdgcn_s_sleep(2);
        __threadfence();  // acquire: see other WGs' writes
    }
    __syncthreads();
}

// ---------------- init: zero scalars/slots/barrier, compute maxcap ----------------
__global__ void k_init(float* ws, const float* cap) {
    int t = threadIdx.x;
    for (int i = t; i < 8192; i += 256) ws[i] = 0.f;
    float m = 0.f;
    for (int j = t; j < NN; j += 256) m = fmaxf(m, cap[j]);
    __shared__ float red[4];
    m = wave_max(m);
    if ((t & 63) == 0) red[t >> 6] = m;
    __syncthreads();
    if (t == 0) ws[WS_MAXCAP] = fmaxf(fmaxf(red[0], red[1]), fmaxf(red[2], red[3]));
}

// ---------------- row norms u2 / v2 ----------------
__global__ void k_norms(const float* U, const float* V, float* ws) {
    int wid = threadIdx.x >> 6, lane = threadIdx.x & 63;
    int row = blockIdx.x * 4 + wid;
    const float* src = (row < MM) ? (U + (size_t)row * DD) : (V + (size_t)(row - MM) * DD);
    float2 a = *(const float2*)(src + lane * 2);
    float s = a.x * a.x + a.y * a.y;
    s = wave_sum(s);
    if (lane == 0) {
        if (row < MM) ws[WS_U + row] = s;
        else          ws[WS_V + row - MM] = s;
    }
}

// ---------------- cost GEMM ----------------
__global__ __launch_bounds__(256) void k_cost(const float* U, const float* V, float* cost, float* ws) {
    __shared__ float As[64][65];
    __shared__ float Bs[64][65];
    __shared__ float red[4];
    int t = threadIdx.x;
    int tr0 = (blockIdx.x >> 6) << 6;
    int tc0 = (blockIdx.x & 63) << 6;
    int tx = t & 15, ty = t >> 4;
    float acc[4][4] = {};
    for (int kk = 0; kk < DD; kk += 64) {
        for (int p = 0; p < 4; p++) {
            int f = t * 4 + p * 1024;
            int r = f >> 6, k = f & 63;
            float4 av = *(const float4*)(U + (size_t)(tr0 + r) * DD + kk + k);
            As[r][k] = av.x; As[r][k + 1] = av.y; As[r][k + 2] = av.z; As[r][k + 3] = av.w;
            float4 bv = *(const float4*)(V + (size_t)(tc0 + r) * DD + kk + k);
            Bs[r][k] = bv.x; Bs[r][k + 1] = bv.y; Bs[r][k + 2] = bv.z; Bs[r][k + 3] = bv.w;
        }
        __syncthreads();
        for (int k = 0; k < 64; k++) {
            float av[4], bv[4];
#pragma unroll
            for (int i = 0; i < 4; i++) av[i] = As[ty * 4 + i][k];
#pragma unroll
            for (int j = 0; j < 4; j++) bv[j] = Bs[tx * 4 + j][k];
#pragma unroll
            for (int i = 0; i < 4; i++)
#pragma unroll
                for (int j = 0; j < 4; j++) acc[i][j] += av[i] * bv[j];
        }
        __syncthreads();
    }
    float u2[4], v2[4];
#pragma unroll
    for (int i = 0; i < 4; i++) u2[i] = ws[WS_U + tr0 + ty * 4 + i];
#pragma unroll
    for (int j = 0; j < 4; j++) v2[j] = ws[WS_V + tc0 + tx * 4 + j];
    float lmax = 0.f;
#pragma unroll
    for (int i = 0; i < 4; i++) {
        int gr = tr0 + ty * 4 + i;
#pragma unroll
        for (int j = 0; j < 4; j++) {
            float c = fmaxf(u2[i] + v2[j] - 2.f * acc[i][j], 0.f);
            lmax = fmaxf(lmax, c);
            cost[(size_t)gr * NN + tc0 + tx * 4 + j] = c;
        }
    }
    lmax = wave_max(lmax);
    if ((t & 63) == 0) red[t >> 6] = lmax;
    __syncthreads();
    if (t == 0) {
        lmax = fmaxf(fmaxf(red[0], red[1]), fmaxf(red[2], red[3]));
        atomicMax((unsigned*)&ws[WS_MAXCOST], __float_as_uint(lmax));
    }
}

// ---------------- make K (bf16) + K^T + Ksum ----------------
__global__ __launch_bounds__(256) void k_makeK(const float* cost, const float* cap, float* ws,
                                               ushortT* K, ushortT* KT) {
    __shared__ ushortT tile[64][65];
    __shared__ float red[4];
    int t = threadIdx.x;
    int tr0 = (blockIdx.x >> 6) << 6, tc0 = (blockIdx.x & 63) << 6;
    float inv_mc = 1.f / (__uint_as_float(*(const unsigned*)&ws[WS_MAXCOST]) + TINYX);
    float inv_cap = 1.f / (ws[WS_MAXCAP] + TINYX);
    float lsum = 0.f;
    for (int s = 0; s < 16; s++) {
        int lr = s * 4 + (t >> 6), lc = t & 63;
        int gr = tr0 + lr, gc = tc0 + lc;
        float c = cost[(size_t)gr * NN + gc] * inv_mc + STRENGTH * (1.f - cap[gc] * inv_cap);
        float kf = expf(-c * (1.f / EPSX));
        lsum += kf;
        ushortT kb = f2bf(kf);
        K[(size_t)gr * NN + gc] = kb;
        tile[lr][lc] = kb;
    }
    __syncthreads();
    for (int s = 0; s < 16; s++) {
        int lr = s * 4 + (t >> 6), lc = t & 63;
        KT[(size_t)(tc0 + lr) * MM + tr0 + lc] = tile[lc][lr];
    }
    lsum = wave_sum(lsum);
    if ((t & 63) == 0) red[t >> 6] = lsum;
    __syncthreads();
    if (t == 0)
        atomicAdd(&ws[WS_KSUM_SLOTS + (blockIdx.x & 63)], red[0] + red[1] + red[2] + red[3]);
}

// ======================= cooperative persistent loop kernel =======================
// 256 WGs x 512 threads. WG owns rows bid*4..+3 and cols bid*16..+15.
__global__ __launch_bounds__(NTHR, 1) void k_loop(const ushortT* __restrict__ K,
                                                  const ushortT* __restrict__ KT,
                                                  const float* __restrict__ a,
                                                  const float* __restrict__ b,
                                                  const float* __restrict__ mbp,
                                                  float* __restrict__ wsf,
                                                  float* __restrict__ out) {
    __shared__ float lv[4096];
    __shared__ float lu[1024];
    __shared__ float red[8];
    __shared__ float gred[8];
    __shared__ float cws[16];
    __shared__ float sh0;

    unsigned* wsu = (unsigned*)wsf;
    int t = threadIdx.x, lane = t & 63, wid = t >> 6;
    int bid = blockIdx.x;
    float mb = mbp[0];
    float* plan = out + 1;
    float* usage = out + 2 + (size_t)MM * NN;
    unsigned barcnt = 0;

    // ---- phase 0: u = mb/Ksum, v = 1 ----
    if (t < 64) {
        float s = wsf[WS_KSUM_SLOTS + t];
        s = wave_sum(s);
        if (t == 0) sh0 = mb / (s + TINYX);
    }
    __syncthreads();
    float s0 = sh0;
    if (t < 4)  wsf[WSN_U + (bid << 2) + t] = s0;
    if (t < 16) wsf[WSN_V + (bid << 4) + t] = 1.f;
    grid_bar(wsu, ++barcnt);

    // ---- main loop ----
    for (int it = 0; it <= NITER; ++it) {
        // ===== row pass: stage v + g-parts =====
        {
            const float4* vg = (const float4*)(wsf + WSN_V);
            float4 x0 = vg[t];
            float4 x1 = vg[t + 512];
            *(float4*)&lv[t * 4] = x0;
            *(float4*)&lv[2048 + t * 4] = x1;
        }
        float gp = 0.f;
        if (it > 0 && t < 256) gp = wsf[WSN_T + ((it - 1) & 1) * 256 + t];
        gp = wave_sum(gp);
        if (lane == 0) gred[wid] = gp;
        __syncthreads();
        float g = 1.f;
        if (it > 0) {
            float ts = gred[0] + gred[1] + gred[2] + gred[3] +
                       gred[4] + gred[5] + gred[6] + gred[7];
            g = mb / (ts + TINYX);
        }
        // dot: wave pair per row (half-row each)
        {
            int i = (bid << 2) + (wid >> 1);
            int j0 = (wid & 1) << 11;
            const unsigned* Kr = (const unsigned*)(K + ((size_t)i << 12) + j0);
            float s = 0.f;
#pragma unroll
            for (int p = 0; p < 16; ++p) {
                unsigned kk = Kr[(p << 6) + lane];
                float2 vv = *(const float2*)&lv[j0 + (((p << 6) + lane) << 1)];
                s = fmaf(__uint_as_float(kk << 16), vv.x, s);
                s = fmaf(__uint_as_float(kk & 0xffff0000u), vv.y, s);
            }
            s = wave_sum(s);
            if (lane == 0) red[wid] = s;
        }
        __syncthreads();
        if (t < 4) {
            int i = (bid << 2) + t;
            float y = red[2 * t] + red[2 * t + 1];
            float ue = wsf[WSN_U + i] * g;
            float rr = ue * y;
            wsf[WSN_U + i] = ue * fminf(a[i] / (rr + TINYX), 1.f);
        }
        grid_bar(wsu, ++barcnt);

        // ===== col pass: stage u =====
        if (t < 256) *(float4*)&lu[t * 4] = *(const float4*)&wsf[WSN_U + t * 4];
        __syncthreads();
        int jb = (bid << 4) + (wid << 1);
        for (int c = 0; c < 2; ++c) {
            int j = jb + c;
            const unsigned* Kc = (const unsigned*)(KT + ((size_t)j << 10));
            float s = 0.f;
#pragma unroll
            for (int p = 0; p < 8; ++p) {
                unsigned kk = Kc[(p << 6) + lane];
                float2 uu = *(const float2*)&lu[((p << 6) + lane) << 1];
                s = fmaf(__uint_as_float(kk << 16), uu.x, s);
                s = fmaf(__uint_as_float(kk & 0xffff0000u), uu.y, s);
            }
            s = wave_sum(s);
            if (lane == 0) {
                float vj = wsf[WSN_V + j];
                float cc = vj * s;
                float sc = fminf(b[j] / (cc + TINYX), 1.f);
                wsf[WSN_V + j] = vj * sc;
                float cw = cc * sc;
                cws[(wid << 1) + c] = cw;
                if (it == NITER) usage[j] = cw;
            }
        }
        __syncthreads();
        if (t == 0) {
            float ts = 0.f;
#pragma unroll
            for (int q = 0; q < 16; ++q) ts += cws[q];
            wsf[WSN_T + (it & 1) * 256 + bid] = ts;
        }
        grid_bar(wsu, ++barcnt);
    }

    // ---- writeback: plan = K*u*v, score partial ----
    {
        const float4* vg = (const float4*)(wsf + WSN_V);
        float4 x0 = vg[t];
        float4 x1 = vg[t + 512];
        *(float4*)&lv[t * 4] = x0;
        *(float4*)&lv[2048 + t * 4] = x1;
    }
    __syncthreads();
    float sc = 0.f;
    for (int r = 0; r < 4; ++r) {
        int i = (bid << 2) + r;
        float ui = wsf[WSN_U + i];
        const unsigned* Kr = (const unsigned*)(K + ((size_t)i << 12));
        float* Pr = plan + ((size_t)i << 12);
#pragma unroll
        for (int q = 0; q < 4; ++q) {
            int s2 = t + (q << 9);
            unsigned kk = Kr[s2];
            float k0 = __uint_as_float(kk << 16);
            float k1 = __uint_as_float(kk & 0xffff0000u);
            float2 vv = *(const float2*)&lv[s2 << 1];
            float p0 = k0 * ui * vv.x;
            float p1 = k1 * ui * vv.y;
            Pr[(s2 << 1)] = p0;
            Pr[(s2 << 1) + 1] = p1;
            sc += p0 * __logf(k0) + p1 * __logf(k1);
        }
    }
    sc = wave_sum(sc);
    if (lane == 0) red[wid] = sc;
    __syncthreads();
    if (t == 0) {
        float st = 0.f;
#pragma unroll
        for (int q = 0; q < 8; ++q) st += red[q];
        wsf[WSN_SC + bid] = st;
    }
    grid_bar(wsu, ++barcnt);

    // ---- epilogue by WG0 ----
    if (bid == 0) {
        float sp = 0.f, tp = 0.f;
        if (t < 256) {
            sp = wsf[WSN_SC + t];
            tp = wsf[WSN_T + (NITER & 1) * 256 + t];
        }
        sp = wave_sum(sp);
        tp = wave_sum(tp);
        if (lane == 0) { red[wid] = sp; gred[wid] = tp; }
        __syncthreads();
        if (t == 0) {
            float ssum = red[0] + red[1] + red[2] + red[3] + red[4] + red[5] + red[6] + red[7];
            float tsum = gred[0] + gred[1] + gred[2] + gred[3] + gred[4] + gred[5] + gred[6] + gred[7];
            out[0] = EPSX * ssum;
            out[1 + (size_t)MM * NN] = tsum;
        }
    }
}

// ======================= f32 fallback (small ws) — round-1 proven =======================
__global__ void k_makeK_f32(float* costK, const float* cap, float* ws) {
    __shared__ float red[4];
    int t = threadIdx.x;
    float inv_mc = 1.f / (__uint_as_float(*(const unsigned*)&ws[WS_MAXCOST]) + TINYX);
    float inv_cap = 1.f / (ws[WS_MAXCAP] + TINYX);
    float lsum = 0.f;
    for (int s = 0; s < 4; s++) {
        size_t idx = (size_t)blockIdx.x * 1024 + s * 256 + t;
        int gc = (int)(idx & (NN - 1));
        float c = costK[idx] * inv_mc + STRENGTH * (1.f - cap[gc] * inv_cap);
        float kf = expf(-c * (1.f / EPSX));
        costK[idx] = kf;
        lsum += kf;
    }
    lsum = wave_sum(lsum);
    if ((t & 63) == 0) red[t >> 6] = lsum;
    __syncthreads();
    if (t == 0)
        atomicAdd(&ws[WS_KSUM_SLOTS + (blockIdx.x & 63)], red[0] + red[1] + red[2] + red[3]);
}

__global__ void k_init_uv(float* ws, const float* mbp) {
    __shared__ float s0s;
    int t = threadIdx.x;
    if (t < 64) {
        float s = ws[WS_KSUM_SLOTS + t];
        s = wave_sum(s);
        if (t == 0) s0s = mbp[0] / (s + TINYX);
    }
    __syncthreads();
    float s0 = s0s;
    for (int i = t; i < MM; i += 256) ws[WS_U + i] = s0;
    for (int j = t; j < NN; j += 256) ws[WS_V + j] = 1.f;
}

__global__ __launch_bounds__(256) void k_row_f32(const float* K, const float* a, const float* mbp,
                                                 float* ws, int iter) {
    __shared__ float red[4];
    int t = threadIdx.x, i = blockIdx.x;
    const float* Krow = K + (size_t)i * NN;
    const float* v = ws + WS_V;
    float s = 0.f;
    for (int p = 0; p < 16; p++) {
        int j = t + p * 256;
        s += Krow[j] * v[j];
    }
    s = wave_sum(s);
    if ((t & 63) == 0) red[t >> 6] = s;
    __syncthreads();
    if (blockIdx.x == 0 && t >= 64 && t < 128) ws[WS_T_SLOTS + (iter & 1) * 64 + t - 64] = 0.f;
    if (t < 64) {
        float y = red[0] + red[1] + red[2] + red[3];
        float g = 1.f;
        if (iter > 0) {
            float tp = ws[WS_T_SLOTS + ((iter - 1) & 1) * 64 + t];
            tp = wave_sum(tp);
            g = mbp[0] / (tp + TINYX);
        }
        if (t == 0) {
            float ue = ws[WS_U + i] * g;
            float r = ue * y;
            ws[WS_U + i] = ue * fminf(a[i] / (r + TINYX), 1.f);
        }
    }
}

__global__ __launch_bounds__(256) void k_col_f32(const float* K, const float* b, float* ws,
                                                 int iter, float* usage_out) {
    __shared__ float red[4];
    int t = threadIdx.x;
    int j = blockIdx.x * 256 + t;
    const float* u = ws + WS_U;
    float s = 0.f;
    for (int i = 0; i < MM; i++) s += K[(size_t)i * NN + j] * u[i];
    float vj = ws[WS_V + j];
    float c = vj * s;
    float sc = fminf(b[j] / (c + TINYX), 1.f);
    ws[WS_V + j] = vj * sc;
    float cw = c * sc;
    if (usage_out) usage_out[j] = cw;
    float bs = wave_sum(cw);
    if ((t & 63) == 0) red[t >> 6] = bs;
    __syncthreads();
    if (t == 0)
        atomicAdd(&ws[WS_T_SLOTS + (iter & 1) * 64 + (blockIdx.x & 63)],
                  red[0] + red[1] + red[2] + red[3]);
}

__global__ __launch_bounds__(256) void k_write_f32(float* K, float* ws) {
    __shared__ float red[4];
    int t = threadIdx.x;
    float sc = 0.f;
    for (int s = 0; s < 4; s++) {
        size_t idx = (size_t)blockIdx.x * 256 + (size_t)s * 1048576 + t;
        int i = (int)(idx >> 12), j = (int)(idx & (NN - 1));
        float kf = K[idx];
        float p = kf * ws[WS_U + i] * ws[WS_V + j];
        K[idx] = p;
        sc += p * __logf(kf);
    }
    sc = wave_sum(sc);
    if ((t & 63) == 0) red[t >> 6] = sc;
    __syncthreads();
    if (t == 0)
        atomicAdd(&ws[WS_SCORE_SLOTS + (blockIdx.x & 63)], red[0] + red[1] + red[2] + red[3]);
}

__global__ void k_epi(const float* ws, float* out) {
    int t = threadIdx.x;
    float s = ws[WS_SCORE_SLOTS + t];
    s = wave_sum(s);
    float tt = ws[WS_T_SLOTS + (NITER & 1) * 64 + t];
    tt = wave_sum(tt);
    if (t == 0) {
        out[0] = EPSX * s;
        out[1 + (size_t)MM * NN] = tt;
    }
}

extern "C" void kernel_launch(void* const* d_in, const int* in_sizes, int n_in,
                              void* d_out, int out_size, void* d_ws, size_t ws_size,
                              hipStream_t stream) {
    const float* U = (const float*)d_in[0];
    const float* V = (const float*)d_in[1];
    const float* a = (const float*)d_in[2];
    const float* b = (const float*)d_in[3];
    const float* mb = (const float*)d_in[4];
    float* out = (float*)d_out;
    float* ws = (float*)d_ws;
    float* plan = out + 1;
    float* usage = out + 2 + (size_t)MM * NN;

    bool fast = (ws_size >= FAST_NEED);
    ushortT* K = (ushortT*)((char*)d_ws + K_BYTE_OFF);
    ushortT* KT = K + (size_t)MM * NN;

    k_init<<<1, 256, 0, stream>>>(ws, b);
    k_norms<<<1280, 256, 0, stream>>>(U, V, ws);
    k_cost<<<1024, 256, 0, stream>>>(U, V, plan, ws);

    if (fast) {
        k_makeK<<<1024, 256, 0, stream>>>(plan, b, ws, K, KT);
        const ushortT* Kc = K;
        const ushortT* KTc = KT;
        void* kargs[] = {(void*)&Kc, (void*)&KTc, (void*)&a, (void*)&b,
                         (void*)&mb, (void*)&ws, (void*)&out};
        hipLaunchCooperativeKernel((const void*)k_loop, dim3(NWG), dim3(NTHR),
                                   kargs, 0, stream);
    } else {
        k_makeK_f32<<<4096, 256, 0, stream>>>(plan, b, ws);
        k_init_uv<<<1, 256, 0, stream>>>(ws, mb);
        for (int it = 0; it <= NITER; it++) {
            k_row_f32<<<MM, 256, 0, stream>>>(plan, a, mb, ws, it);
            k_col_f32<<<NN / 256, 256, 0, stream>>>(plan, b, ws, it, (it == NITER) ? usage : nullptr);
        }
        k_write_f32<<<4096, 256, 0, stream>>>(plan, ws);
        k_epi<<<1, 64, 0, stream>>>(ws, out);
    }
}

// Round 3
// 670.745 us; speedup vs baseline: 1.8074x; 1.8074x over previous
//
#include <hip/hip_runtime.h>
#include <hip/hip_bf16.h>
#include <stdint.h>

typedef unsigned short ushortT;

#define MM 1024
#define NN 4096
#define DD 128
#define EPSX 0.05f
#define STRENGTH 0.5f
#define TINYX 1e-12f
#define NITER 50

// ---- prologue + f32 fallback layout ----
#define WS_MAXCOST 0
#define WS_MAXCAP  1
#define WS_KSUM_SLOTS 16   // 64 slots
#define WS_SCORE_SLOTS 80  // 64 slots (fallback)
#define WS_T_SLOTS 144     // 2 x 64 slots (fallback)
#define WS_U 512
#define WS_V 1536
#define K_BYTE_OFF 32768
#define FAST_NEED (32768ull + 2ull * 8388608ull)

// ---- cooperative fast-path layout (float/u32 indices into ws) ----
#define WSN_U  2048        // 1024 floats
#define WSN_V  3072        // 4096 floats (3072..7168)
#define WSN_T  7168        // 2 x 128 per-WG t slots
#define WSN_SC 7680        // 128 per-WG score slots
#define WSB_CNT 7936       // single flat barrier counter (u32)
#define NWG 128
#define NTHR 1024

__device__ inline float bf2f(ushortT u) { return __uint_as_float(((unsigned)u) << 16); }
__device__ inline ushortT f2bf(float f) {
    unsigned b = __float_as_uint(f);
    b += 0x7fffu + ((b >> 16) & 1u);
    return (ushortT)(b >> 16);
}
__device__ inline float wave_sum(float v) {
    for (int o = 32; o; o >>= 1) v += __shfl_down(v, o);
    return v;
}
__device__ inline float wave_max(float v) {
    for (int o = 32; o; o >>= 1) v = fmaxf(v, __shfl_down(v, o));
    return v;
}

// coherent (sc1, MALL-level) scalar access — bypasses L1/L2, no fences needed
__device__ inline void g_store(float* p, float v) {
    __hip_atomic_store(p, v, __ATOMIC_RELAXED, __HIP_MEMORY_SCOPE_AGENT);
}
__device__ inline float g_load(const float* p) {
    return __hip_atomic_load((float*)p, __ATOMIC_RELAXED, __HIP_MEMORY_SCOPE_AGENT);
}

// flat monotonic grid barrier: no fences, no L2 flush.
// __syncthreads() drains each wave's vmcnt before s_barrier (compiler-
// guaranteed), so all sc1 data stores are at the MALL before arrival.
__device__ inline void grid_bar(unsigned* cnt, unsigned round) {
    __syncthreads();
    if (threadIdx.x == 0) {
        asm volatile("s_waitcnt vmcnt(0)" ::: "memory");
        __hip_atomic_fetch_add(cnt, 1u, __ATOMIC_RELAXED, __HIP_MEMORY_SCOPE_AGENT);
        unsigned tgt = round * NWG;
        while (__hip_atomic_load(cnt, __ATOMIC_RELAXED, __HIP_MEMORY_SCOPE_AGENT) < tgt)
            __builtin_amdgcn_s_sleep(2);
        asm volatile("" ::: "memory");
    }
    __syncthreads();
}

// ---------------- init: zero scalars/slots/barrier, compute maxcap ----------------
__global__ void k_init(float* ws, const float* cap) {
    int t = threadIdx.x;
    for (int i = t; i < 8192; i += 256) ws[i] = 0.f;
    float m = 0.f;
    for (int j = t; j < NN; j += 256) m = fmaxf(m, cap[j]);
    __shared__ float red[4];
    m = wave_max(m);
    if ((t & 63) == 0) red[t >> 6] = m;
    __syncthreads();
    if (t == 0) ws[WS_MAXCAP] = fmaxf(fmaxf(red[0], red[1]), fmaxf(red[2], red[3]));
}

// ---------------- row norms u2 / v2 ----------------
__global__ void k_norms(const float* U, const float* V, float* ws) {
    int wid = threadIdx.x >> 6, lane = threadIdx.x & 63;
    int row = blockIdx.x * 4 + wid;
    const float* src = (row < MM) ? (U + (size_t)row * DD) : (V + (size_t)(row - MM) * DD);
    float2 a = *(const float2*)(src + lane * 2);
    float s = a.x * a.x + a.y * a.y;
    s = wave_sum(s);
    if (lane == 0) {
        if (row < MM) ws[WS_U + row] = s;
        else          ws[WS_V + row - MM] = s;
    }
}

// ---------------- cost GEMM ----------------
__global__ __launch_bounds__(256) void k_cost(const float* U, const float* V, float* cost, float* ws) {
    __shared__ float As[64][65];
    __shared__ float Bs[64][65];
    __shared__ float red[4];
    int t = threadIdx.x;
    int tr0 = (blockIdx.x >> 6) << 6;
    int tc0 = (blockIdx.x & 63) << 6;
    int tx = t & 15, ty = t >> 4;
    float acc[4][4] = {};
    for (int kk = 0; kk < DD; kk += 64) {
        for (int p = 0; p < 4; p++) {
            int f = t * 4 + p * 1024;
            int r = f >> 6, k = f & 63;
            float4 av = *(const float4*)(U + (size_t)(tr0 + r) * DD + kk + k);
            As[r][k] = av.x; As[r][k + 1] = av.y; As[r][k + 2] = av.z; As[r][k + 3] = av.w;
            float4 bv = *(const float4*)(V + (size_t)(tc0 + r) * DD + kk + k);
            Bs[r][k] = bv.x; Bs[r][k + 1] = bv.y; Bs[r][k + 2] = bv.z; Bs[r][k + 3] = bv.w;
        }
        __syncthreads();
        for (int k = 0; k < 64; k++) {
            float av[4], bv[4];
#pragma unroll
            for (int i = 0; i < 4; i++) av[i] = As[ty * 4 + i][k];
#pragma unroll
            for (int j = 0; j < 4; j++) bv[j] = Bs[tx * 4 + j][k];
#pragma unroll
            for (int i = 0; i < 4; i++)
#pragma unroll
                for (int j = 0; j < 4; j++) acc[i][j] += av[i] * bv[j];
        }
        __syncthreads();
    }
    float u2[4], v2[4];
#pragma unroll
    for (int i = 0; i < 4; i++) u2[i] = ws[WS_U + tr0 + ty * 4 + i];
#pragma unroll
    for (int j = 0; j < 4; j++) v2[j] = ws[WS_V + tc0 + tx * 4 + j];
    float lmax = 0.f;
#pragma unroll
    for (int i = 0; i < 4; i++) {
        int gr = tr0 + ty * 4 + i;
#pragma unroll
        for (int j = 0; j < 4; j++) {
            float c = fmaxf(u2[i] + v2[j] - 2.f * acc[i][j], 0.f);
            lmax = fmaxf(lmax, c);
            cost[(size_t)gr * NN + tc0 + tx * 4 + j] = c;
        }
    }
    lmax = wave_max(lmax);
    if ((t & 63) == 0) red[t >> 6] = lmax;
    __syncthreads();
    if (t == 0) {
        lmax = fmaxf(fmaxf(red[0], red[1]), fmaxf(red[2], red[3]));
        atomicMax((unsigned*)&ws[WS_MAXCOST], __float_as_uint(lmax));
    }
}

// ---------------- make K (bf16) + K^T + Ksum ----------------
__global__ __launch_bounds__(256) void k_makeK(const float* cost, const float* cap, float* ws,
                                               ushortT* K, ushortT* KT) {
    __shared__ ushortT tile[64][65];
    __shared__ float red[4];
    int t = threadIdx.x;
    int tr0 = (blockIdx.x >> 6) << 6, tc0 = (blockIdx.x & 63) << 6;
    float inv_mc = 1.f / (__uint_as_float(*(const unsigned*)&ws[WS_MAXCOST]) + TINYX);
    float inv_cap = 1.f / (ws[WS_MAXCAP] + TINYX);
    float lsum = 0.f;
    for (int s = 0; s < 16; s++) {
        int lr = s * 4 + (t >> 6), lc = t & 63;
        int gr = tr0 + lr, gc = tc0 + lc;
        float c = cost[(size_t)gr * NN + gc] * inv_mc + STRENGTH * (1.f - cap[gc] * inv_cap);
        float kf = expf(-c * (1.f / EPSX));
        lsum += kf;
        ushortT kb = f2bf(kf);
        K[(size_t)gr * NN + gc] = kb;
        tile[lr][lc] = kb;
    }
    __syncthreads();
    for (int s = 0; s < 16; s++) {
        int lr = s * 4 + (t >> 6), lc = t & 63;
        KT[(size_t)(tc0 + lr) * MM + tr0 + lc] = tile[lc][lr];
    }
    lsum = wave_sum(lsum);
    if ((t & 63) == 0) red[t >> 6] = lsum;
    __syncthreads();
    if (t == 0)
        atomicAdd(&ws[WS_KSUM_SLOTS + (blockIdx.x & 63)], red[0] + red[1] + red[2] + red[3]);
}

// ======================= cooperative persistent loop kernel =======================
// 128 WGs x 1024 threads. WG owns rows bid*8..+7 and cols bid*32..+31.
__global__ __launch_bounds__(NTHR, 1) void k_loop(const ushortT* __restrict__ K,
                                                  const ushortT* __restrict__ KT,
                                                  const float* __restrict__ a,
                                                  const float* __restrict__ b,
                                                  const float* __restrict__ mbp,
                                                  float* __restrict__ wsf,
                                                  float* __restrict__ out) {
    __shared__ float lv[4096];
    __shared__ float lu[1024];
    __shared__ float red[16];
    __shared__ float red2[16];
    __shared__ float cws[32];
    __shared__ float sh0;

    int t = threadIdx.x, lane = t & 63, wid = t >> 6;
    int bid = blockIdx.x;
    unsigned* cnt = (unsigned*)wsf + WSB_CNT;
    float mb = mbp[0];
    float* plan = out + 1;
    float* usage = out + 2 + (size_t)MM * NN;
    int r0 = bid << 3;   // 8 rows
    int c0 = bid << 5;   // 32 cols
    int myj = c0 + (wid << 1);
    unsigned barcnt = 0;

    // persistent owner state in registers
    float a_reg = (t < 8) ? a[r0 + t] : 0.f;
    float b_reg0 = 0.f, b_reg1 = 0.f;
    if (lane == 0) { b_reg0 = b[myj]; b_reg1 = b[myj + 1]; }
    float u_reg = 0.f;
    float v_reg0 = 1.f, v_reg1 = 1.f;

    // ---- phase 0: u = mb/Ksum, v = 1 ----
    if (wid == 0) {
        float s = g_load(wsf + WS_KSUM_SLOTS + lane);
        s = wave_sum(s);
        if (lane == 0) sh0 = mb / (s + TINYX);
    }
    __syncthreads();
    u_reg = sh0;
    if (t < 8) g_store(wsf + WSN_U + r0 + t, u_reg);
    if (lane == 0) {
        g_store(wsf + WSN_V + myj, 1.f);
        g_store(wsf + WSN_V + myj + 1, 1.f);
    }
    grid_bar(cnt, ++barcnt);

    // ---- main loop ----
    for (int it = 0; it <= NITER; ++it) {
        // ===== row pass: stage v (sc1), fold g, dot, row clip =====
        {
            int j4 = t << 2;
            float x0 = g_load(wsf + WSN_V + j4);
            float x1 = g_load(wsf + WSN_V + j4 + 1);
            float x2 = g_load(wsf + WSN_V + j4 + 2);
            float x3 = g_load(wsf + WSN_V + j4 + 3);
            lv[j4] = x0; lv[j4 + 1] = x1; lv[j4 + 2] = x2; lv[j4 + 3] = x3;
        }
        if (wid < 2) {
            float gp = (it > 0) ? g_load(wsf + WSN_T + ((it - 1) & 1) * 128 + (wid << 6) + lane)
                                : 0.f;
            gp = wave_sum(gp);
            if (lane == 0) red2[wid] = gp;
        }
        __syncthreads();
        float g = (it > 0) ? (mb / (red2[0] + red2[1] + TINYX)) : 1.f;
        {
            int i = r0 + (wid >> 1);
            int dw0 = (wid & 1) << 10;
            const unsigned* Kr = (const unsigned*)K + ((size_t)i << 11);
            float s = 0.f;
#pragma unroll
            for (int p = 0; p < 16; ++p) {
                int dw = dw0 + (p << 6) + lane;
                unsigned kk = Kr[dw];
                float2 vv = *(const float2*)&lv[dw << 1];
                s = fmaf(__uint_as_float(kk << 16), vv.x, s);
                s = fmaf(__uint_as_float(kk & 0xffff0000u), vv.y, s);
            }
            s = wave_sum(s);
            if (lane == 0) red[wid] = s;
        }
        __syncthreads();
        if (t < 8) {
            float y = red[2 * t] + red[2 * t + 1];
            float ue = u_reg * g;
            float rr = ue * y;
            u_reg = ue * fminf(a_reg / (rr + TINYX), 1.f);
            g_store(wsf + WSN_U + r0 + t, u_reg);
        }
        grid_bar(cnt, ++barcnt);

        // ===== col pass: stage u (sc1), dot, col clip, t partial =====
        lu[t] = g_load(wsf + WSN_U + t);
        __syncthreads();
#pragma unroll
        for (int c = 0; c < 2; ++c) {
            int j = myj + c;
            const unsigned* Kc = (const unsigned*)KT + ((size_t)j << 9);
            float s = 0.f;
#pragma unroll
            for (int p = 0; p < 8; ++p) {
                int dw = (p << 6) + lane;
                unsigned kk = Kc[dw];
                float2 uu = *(const float2*)&lu[dw << 1];
                s = fmaf(__uint_as_float(kk << 16), uu.x, s);
                s = fmaf(__uint_as_float(kk & 0xffff0000u), uu.y, s);
            }
            s = wave_sum(s);
            if (lane == 0) {
                float vj = (c == 0) ? v_reg0 : v_reg1;
                float cc = vj * s;
                float bj = (c == 0) ? b_reg0 : b_reg1;
                float scv = fminf(bj / (cc + TINYX), 1.f);
                float vn = vj * scv;
                if (c == 0) v_reg0 = vn; else v_reg1 = vn;
                g_store(wsf + WSN_V + j, vn);
                float cw = cc * scv;
                cws[(wid << 1) + c] = cw;
                if (it == NITER) usage[j] = cw;
            }
        }
        __syncthreads();
        if (t == 0) {
            float ts = 0.f;
#pragma unroll
            for (int q = 0; q < 32; ++q) ts += cws[q];
            g_store(wsf + WSN_T + (it & 1) * 128 + bid, ts);
        }
        grid_bar(cnt, ++barcnt);
    }

    // ---- writeback: plan = K*u*v, score partial ----
    lu[t] = g_load(wsf + WSN_U + t);
    {
        int j4 = t << 2;
        float x0 = g_load(wsf + WSN_V + j4);
        float x1 = g_load(wsf + WSN_V + j4 + 1);
        float x2 = g_load(wsf + WSN_V + j4 + 2);
        float x3 = g_load(wsf + WSN_V + j4 + 3);
        lv[j4] = x0; lv[j4 + 1] = x1; lv[j4 + 2] = x2; lv[j4 + 3] = x3;
    }
    __syncthreads();
    float sc = 0.f;
    for (int r = 0; r < 8; ++r) {
        int i = r0 + r;
        float ui = lu[i];
        const unsigned* Kr = (const unsigned*)K + ((size_t)i << 11);
        float2* Pr = (float2*)(plan + ((size_t)i << 12));
#pragma unroll
        for (int q = 0; q < 2; ++q) {
            int dw = t + (q << 10);
            unsigned kk = Kr[dw];
            float k0 = __uint_as_float(kk << 16);
            float k1 = __uint_as_float(kk & 0xffff0000u);
            float2 vv = *(const float2*)&lv[dw << 1];
            float p0 = k0 * ui * vv.x;
            float p1 = k1 * ui * vv.y;
            Pr[dw] = make_float2(p0, p1);
            sc += p0 * __logf(k0) + p1 * __logf(k1);
        }
    }
    sc = wave_sum(sc);
    if (lane == 0) red[wid] = sc;
    __syncthreads();
    if (t == 0) {
        float st = 0.f;
#pragma unroll
        for (int q = 0; q < 16; ++q) st += red[q];
        g_store(wsf + WSN_SC + bid, st);
    }
    grid_bar(cnt, ++barcnt);

    // ---- epilogue by WG0 ----
    if (bid == 0) {
        if (wid < 2) {
            float sp = g_load(wsf + WSN_SC + (wid << 6) + lane);
            float tp = g_load(wsf + WSN_T + (NITER & 1) * 128 + (wid << 6) + lane);
            sp = wave_sum(sp);
            tp = wave_sum(tp);
            if (lane == 0) { red[wid] = sp; red2[wid] = tp; }
        }
        __syncthreads();
        if (t == 0) {
            out[0] = EPSX * (red[0] + red[1]);
            out[1 + (size_t)MM * NN] = red2[0] + red2[1];
        }
    }
}

// ======================= f32 fallback (small ws) — round-1 proven =======================
__global__ void k_makeK_f32(float* costK, const float* cap, float* ws) {
    __shared__ float red[4];
    int t = threadIdx.x;
    float inv_mc = 1.f / (__uint_as_float(*(const unsigned*)&ws[WS_MAXCOST]) + TINYX);
    float inv_cap = 1.f / (ws[WS_MAXCAP] + TINYX);
    float lsum = 0.f;
    for (int s = 0; s < 4; s++) {
        size_t idx = (size_t)blockIdx.x * 1024 + s * 256 + t;
        int gc = (int)(idx & (NN - 1));
        float c = costK[idx] * inv_mc + STRENGTH * (1.f - cap[gc] * inv_cap);
        float kf = expf(-c * (1.f / EPSX));
        costK[idx] = kf;
        lsum += kf;
    }
    lsum = wave_sum(lsum);
    if ((t & 63) == 0) red[t >> 6] = lsum;
    __syncthreads();
    if (t == 0)
        atomicAdd(&ws[WS_KSUM_SLOTS + (blockIdx.x & 63)], red[0] + red[1] + red[2] + red[3]);
}

__global__ void k_init_uv(float* ws, const float* mbp) {
    __shared__ float s0s;
    int t = threadIdx.x;
    if (t < 64) {
        float s = ws[WS_KSUM_SLOTS + t];
        s = wave_sum(s);
        if (t == 0) s0s = mbp[0] / (s + TINYX);
    }
    __syncthreads();
    float s0 = s0s;
    for (int i = t; i < MM; i += 256) ws[WS_U + i] = s0;
    for (int j = t; j < NN; j += 256) ws[WS_V + j] = 1.f;
}

__global__ __launch_bounds__(256) void k_row_f32(const float* K, const float* a, const float* mbp,
                                                 float* ws, int iter) {
    __shared__ float red[4];
    int t = threadIdx.x, i = blockIdx.x;
    const float* Krow = K + (size_t)i * NN;
    const float* v = ws + WS_V;
    float s = 0.f;
    for (int p = 0; p < 16; p++) {
        int j = t + p * 256;
        s += Krow[j] * v[j];
    }
    s = wave_sum(s);
    if ((t & 63) == 0) red[t >> 6] = s;
    __syncthreads();
    if (blockIdx.x == 0 && t >= 64 && t < 128) ws[WS_T_SLOTS + (iter & 1) * 64 + t - 64] = 0.f;
    if (t < 64) {
        float y = red[0] + red[1] + red[2] + red[3];
        float g = 1.f;
        if (iter > 0) {
            float tp = ws[WS_T_SLOTS + ((iter - 1) & 1) * 64 + t];
            tp = wave_sum(tp);
            g = mbp[0] / (tp + TINYX);
        }
        if (t == 0) {
            float ue = ws[WS_U + i] * g;
            float r = ue * y;
            ws[WS_U + i] = ue * fminf(a[i] / (r + TINYX), 1.f);
        }
    }
}

__global__ __launch_bounds__(256) void k_col_f32(const float* K, const float* b, float* ws,
                                                 int iter, float* usage_out) {
    __shared__ float red[4];
    int t = threadIdx.x;
    int j = blockIdx.x * 256 + t;
    const float* u = ws + WS_U;
    float s = 0.f;
    for (int i = 0; i < MM; i++) s += K[(size_t)i * NN + j] * u[i];
    float vj = ws[WS_V + j];
    float c = vj * s;
    float sc = fminf(b[j] / (c + TINYX), 1.f);
    ws[WS_V + j] = vj * sc;
    float cw = c * sc;
    if (usage_out) usage_out[j] = cw;
    float bs = wave_sum(cw);
    if ((t & 63) == 0) red[t >> 6] = bs;
    __syncthreads();
    if (t == 0)
        atomicAdd(&ws[WS_T_SLOTS + (iter & 1) * 64 + (blockIdx.x & 63)],
                  red[0] + red[1] + red[2] + red[3]);
}

__global__ __launch_bounds__(256) void k_write_f32(float* K, float* ws) {
    __shared__ float red[4];
    int t = threadIdx.x;
    float sc = 0.f;
    for (int s = 0; s < 4; s++) {
        size_t idx = (size_t)blockIdx.x * 256 + (size_t)s * 1048576 + t;
        int i = (int)(idx >> 12), j = (int)(idx & (NN - 1));
        float kf = K[idx];
        float p = kf * ws[WS_U + i] * ws[WS_V + j];
        K[idx] = p;
        sc += p * __logf(kf);
    }
    sc = wave_sum(sc);
    if ((t & 63) == 0) red[t >> 6] = sc;
    __syncthreads();
    if (t == 0)
        atomicAdd(&ws[WS_SCORE_SLOTS + (blockIdx.x & 63)], red[0] + red[1] + red[2] + red[3]);
}

__global__ void k_epi(const float* ws, float* out) {
    int t = threadIdx.x;
    float s = ws[WS_SCORE_SLOTS + t];
    s = wave_sum(s);
    float tt = ws[WS_T_SLOTS + (NITER & 1) * 64 + t];
    tt = wave_sum(tt);
    if (t == 0) {
        out[0] = EPSX * s;
        out[1 + (size_t)MM * NN] = tt;
    }
}

extern "C" void kernel_launch(void* const* d_in, const int* in_sizes, int n_in,
                              void* d_out, int out_size, void* d_ws, size_t ws_size,
                              hipStream_t stream) {
    const float* U = (const float*)d_in[0];
    const float* V = (const float*)d_in[1];
    const float* a = (const float*)d_in[2];
    const float* b = (const float*)d_in[3];
    const float* mb = (const float*)d_in[4];
    float* out = (float*)d_out;
    float* ws = (float*)d_ws;
    float* plan = out + 1;
    float* usage = out + 2 + (size_t)MM * NN;

    bool fast = (ws_size >= FAST_NEED);
    ushortT* K = (ushortT*)((char*)d_ws + K_BYTE_OFF);
    ushortT* KT = K + (size_t)MM * NN;

    k_init<<<1, 256, 0, stream>>>(ws, b);
    k_norms<<<1280, 256, 0, stream>>>(U, V, ws);
    k_cost<<<1024, 256, 0, stream>>>(U, V, plan, ws);

    if (fast) {
        k_makeK<<<1024, 256, 0, stream>>>(plan, b, ws, K, KT);
        const ushortT* Kc = K;
        const ushortT* KTc = KT;
        void* kargs[] = {(void*)&Kc, (void*)&KTc, (void*)&a, (void*)&b,
                         (void*)&mb, (void*)&ws, (void*)&out};
        hipLaunchCooperativeKernel((const void*)k_loop, dim3(NWG), dim3(NTHR),
                                   kargs, 0, stream);
    } else {
        k_makeK_f32<<<4096, 256, 0, stream>>>(plan, b, ws);
        k_init_uv<<<1, 256, 0, stream>>>(ws, mb);
        for (int it = 0; it <= NITER; it++) {
            k_row_f32<<<MM, 256, 0, stream>>>(plan, a, mb, ws, it);
            k_col_f32<<<NN / 256, 256, 0, stream>>>(plan, b, ws, it, (it == NITER) ? usage : nullptr);
        }
        k_write_f32<<<4096, 256, 0, stream>>>(plan, ws);
        k_epi<<<1, 64, 0, stream>>>(ws, out);
    }
}

// Round 4
// 507.496 us; speedup vs baseline: 2.3888x; 1.3217x over previous
//
#include <hip/hip_runtime.h>
#include <hip/hip_bf16.h>
#include <stdint.h>

typedef unsigned short ushortT;
typedef float f32x4 __attribute__((ext_vector_type(4)));
typedef float f32x2 __attribute__((ext_vector_type(2)));

#define MM 1024
#define NN 4096
#define DD 128
#define EPSX 0.05f
#define STRENGTH 0.5f
#define TINYX 1e-12f
#define NITER 50

// ---- prologue + f32 fallback layout (float indices into ws) ----
#define WS_MAXCOST 0
#define WS_MAXCAP  1
#define WS_KSUM_SLOTS 16   // 64 slots
#define WS_SCORE_SLOTS 80  // 64 slots (fallback)
#define WS_T_SLOTS 144     // 2 x 64 slots (fallback)
#define WS_U 512           // u2 (prologue) / fallback u
#define WS_V 1536          // v2 (prologue) / fallback v
#define K_BYTE_OFF 32768
#define FAST_NEED (32768ull + 2ull * 8388608ull)

// ---- cooperative fast-path layout (all < 8192 floats = 32 KB) ----
#define WSN_U   1024       // 1024 floats (overwritten in phase 0)
#define WSN_V   2048       // 4096 floats (overwritten in phase 0)
#define WSN_T   6144       // 2 x 256 per-WG t slots
#define WSN_SC  6656       // 256 per-WG score slots
#define WSB_SUB 6912       // 8 sub-counters, stride 32 u32 (128 B)
#define WSB_MST 7168       // master counter (own line)
#define NWG 256
#define NTHR 512

__device__ inline float bf2f(ushortT u) { return __uint_as_float(((unsigned)u) << 16); }
__device__ inline ushortT f2bf(float f) {
    unsigned b = __float_as_uint(f);
    b += 0x7fffu + ((b >> 16) & 1u);
    return (ushortT)(b >> 16);
}
__device__ inline float wave_sum(float v) {
    for (int o = 32; o; o >>= 1) v += __shfl_down(v, o);
    return v;
}
__device__ inline float wave_max(float v) {
    for (int o = 32; o; o >>= 1) v = fmaxf(v, __shfl_down(v, o));
    return v;
}

// coherent (sc1 / MALL-level) scalar access — bypasses L1/L2, no fences needed
__device__ inline void g_store(float* p, float v) {
    __hip_atomic_store(p, v, __ATOMIC_RELAXED, __HIP_MEMORY_SCOPE_AGENT);
}
__device__ inline float g_load(const float* p) {
    return __hip_atomic_load((float*)p, __ATOMIC_RELAXED, __HIP_MEMORY_SCOPE_AGENT);
}

// vectorized coherent staging: 2x dwordx4 sc1 loads, single wait
__device__ inline void stage_v8(const float* vbase, int t, float* lv) {
    f32x4 x0, x1;
    const float* p0 = vbase + (t << 3);
    const float* p1 = p0 + 4;
    asm volatile(
        "global_load_dwordx4 %0, %2, off sc1\n\t"
        "global_load_dwordx4 %1, %3, off sc1\n\t"
        "s_waitcnt vmcnt(0)"
        : "=&v"(x0), "=&v"(x1) : "v"(p0), "v"(p1) : "memory");
    *(f32x4*)&lv[t << 3] = x0;
    *(f32x4*)&lv[(t << 3) + 4] = x1;
}
__device__ inline void stage_u2(const float* ubase, int t, float* lu) {
    f32x2 x0;
    const float* p0 = ubase + (t << 1);
    asm volatile(
        "global_load_dwordx2 %0, %1, off sc1\n\t"
        "s_waitcnt vmcnt(0)"
        : "=&v"(x0) : "v"(p0) : "memory");
    *(f32x2*)&lu[t << 1] = x0;
}

// two-level monotonic grid barrier: no fences, no L2 flush.
__device__ inline void grid_bar(unsigned* w, unsigned round) {
    __syncthreads();
    if (threadIdx.x == 0) {
        asm volatile("s_waitcnt vmcnt(0)" ::: "memory");
        int sg = blockIdx.x & 7;
        unsigned prev = __hip_atomic_fetch_add(&w[WSB_SUB + sg * 32], 1u,
                                               __ATOMIC_RELAXED, __HIP_MEMORY_SCOPE_AGENT);
        if (prev + 1u == round * (NWG / 8))
            __hip_atomic_fetch_add(&w[WSB_MST], 1u,
                                   __ATOMIC_RELAXED, __HIP_MEMORY_SCOPE_AGENT);
        while (__hip_atomic_load(&w[WSB_MST], __ATOMIC_RELAXED,
                                 __HIP_MEMORY_SCOPE_AGENT) < round * 8u)
            __builtin_amdgcn_s_sleep(1);
        asm volatile("" ::: "memory");
    }
    __syncthreads();
}

// ---------------- init: zero scalars/slots/barrier, compute maxcap ----------------
__global__ void k_init(float* ws, const float* cap) {
    int t = threadIdx.x;
    for (int i = t; i < 8192; i += 256) ws[i] = 0.f;
    float m = 0.f;
    for (int j = t; j < NN; j += 256) m = fmaxf(m, cap[j]);
    __shared__ float red[4];
    m = wave_max(m);
    if ((t & 63) == 0) red[t >> 6] = m;
    __syncthreads();
    if (t == 0) ws[WS_MAXCAP] = fmaxf(fmaxf(red[0], red[1]), fmaxf(red[2], red[3]));
}

// ---------------- row norms u2 / v2 ----------------
__global__ void k_norms(const float* U, const float* V, float* ws) {
    int wid = threadIdx.x >> 6, lane = threadIdx.x & 63;
    int row = blockIdx.x * 4 + wid;
    const float* src = (row < MM) ? (U + (size_t)row * DD) : (V + (size_t)(row - MM) * DD);
    float2 a = *(const float2*)(src + lane * 2);
    float s = a.x * a.x + a.y * a.y;
    s = wave_sum(s);
    if (lane == 0) {
        if (row < MM) ws[WS_U + row] = s;
        else          ws[WS_V + row - MM] = s;
    }
}

// ---------------- cost GEMM ----------------
__global__ __launch_bounds__(256) void k_cost(const float* U, const float* V, float* cost, float* ws) {
    __shared__ float As[64][65];
    __shared__ float Bs[64][65];
    __shared__ float red[4];
    int t = threadIdx.x;
    int tr0 = (blockIdx.x >> 6) << 6;
    int tc0 = (blockIdx.x & 63) << 6;
    int tx = t & 15, ty = t >> 4;
    float acc[4][4] = {};
    for (int kk = 0; kk < DD; kk += 64) {
        for (int p = 0; p < 4; p++) {
            int f = t * 4 + p * 1024;
            int r = f >> 6, k = f & 63;
            float4 av = *(const float4*)(U + (size_t)(tr0 + r) * DD + kk + k);
            As[r][k] = av.x; As[r][k + 1] = av.y; As[r][k + 2] = av.z; As[r][k + 3] = av.w;
            float4 bv = *(const float4*)(V + (size_t)(tc0 + r) * DD + kk + k);
            Bs[r][k] = bv.x; Bs[r][k + 1] = bv.y; Bs[r][k + 2] = bv.z; Bs[r][k + 3] = bv.w;
        }
        __syncthreads();
        for (int k = 0; k < 64; k++) {
            float av[4], bv[4];
#pragma unroll
            for (int i = 0; i < 4; i++) av[i] = As[ty * 4 + i][k];
#pragma unroll
            for (int j = 0; j < 4; j++) bv[j] = Bs[tx * 4 + j][k];
#pragma unroll
            for (int i = 0; i < 4; i++)
#pragma unroll
                for (int j = 0; j < 4; j++) acc[i][j] += av[i] * bv[j];
        }
        __syncthreads();
    }
    float u2[4], v2[4];
#pragma unroll
    for (int i = 0; i < 4; i++) u2[i] = ws[WS_U + tr0 + ty * 4 + i];
#pragma unroll
    for (int j = 0; j < 4; j++) v2[j] = ws[WS_V + tc0 + tx * 4 + j];
    float lmax = 0.f;
#pragma unroll
    for (int i = 0; i < 4; i++) {
        int gr = tr0 + ty * 4 + i;
#pragma unroll
        for (int j = 0; j < 4; j++) {
            float c = fmaxf(u2[i] + v2[j] - 2.f * acc[i][j], 0.f);
            lmax = fmaxf(lmax, c);
            cost[(size_t)gr * NN + tc0 + tx * 4 + j] = c;
        }
    }
    lmax = wave_max(lmax);
    if ((t & 63) == 0) red[t >> 6] = lmax;
    __syncthreads();
    if (t == 0) {
        lmax = fmaxf(fmaxf(red[0], red[1]), fmaxf(red[2], red[3]));
        atomicMax((unsigned*)&ws[WS_MAXCOST], __float_as_uint(lmax));
    }
}

// ---------------- make K (bf16) + K^T + Ksum ----------------
__global__ __launch_bounds__(256) void k_makeK(const float* cost, const float* cap, float* ws,
                                               ushortT* K, ushortT* KT) {
    __shared__ ushortT tile[64][65];
    __shared__ float red[4];
    int t = threadIdx.x;
    int tr0 = (blockIdx.x >> 6) << 6, tc0 = (blockIdx.x & 63) << 6;
    float inv_mc = 1.f / (__uint_as_float(*(const unsigned*)&ws[WS_MAXCOST]) + TINYX);
    float inv_cap = 1.f / (ws[WS_MAXCAP] + TINYX);
    float lsum = 0.f;
    for (int s = 0; s < 16; s++) {
        int lr = s * 4 + (t >> 6), lc = t & 63;
        int gr = tr0 + lr, gc = tc0 + lc;
        float c = cost[(size_t)gr * NN + gc] * inv_mc + STRENGTH * (1.f - cap[gc] * inv_cap);
        float kf = expf(-c * (1.f / EPSX));
        lsum += kf;
        ushortT kb = f2bf(kf);
        K[(size_t)gr * NN + gc] = kb;
        tile[lr][lc] = kb;
    }
    __syncthreads();
    for (int s = 0; s < 16; s++) {
        int lr = s * 4 + (t >> 6), lc = t & 63;
        KT[(size_t)(tc0 + lr) * MM + tr0 + lc] = tile[lc][lr];
    }
    lsum = wave_sum(lsum);
    if ((t & 63) == 0) red[t >> 6] = lsum;
    __syncthreads();
    if (t == 0)
        atomicAdd(&ws[WS_KSUM_SLOTS + (blockIdx.x & 63)], red[0] + red[1] + red[2] + red[3]);
}

// ======================= cooperative persistent loop kernel =======================
// 256 WGs x 512 threads. WG owns rows bid*4..+3 and cols bid*16..+15.
__global__ __launch_bounds__(NTHR, 1) void k_loop(const ushortT* __restrict__ K,
                                                  const ushortT* __restrict__ KT,
                                                  const float* __restrict__ a,
                                                  const float* __restrict__ b,
                                                  const float* __restrict__ mbp,
                                                  float* __restrict__ wsf,
                                                  float* __restrict__ out) {
    __shared__ __align__(16) float lv[4096];
    __shared__ __align__(16) float lu[1024];
    __shared__ float red[8];
    __shared__ float gred[8];
    __shared__ float red2[8];
    __shared__ float cws[16];
    __shared__ float sh0;

    int t = threadIdx.x, lane = t & 63, wid = t >> 6;
    int bid = blockIdx.x;
    unsigned* cnt = (unsigned*)wsf;
    float mb = mbp[0];
    float* plan = out + 1;
    float* usage = out + 2 + (size_t)MM * NN;
    int r0 = bid << 2;   // 4 rows
    int c0 = bid << 4;   // 16 cols
    int j0 = c0 + (wid << 1);   // this wave's 2 cols
    unsigned barcnt = 0;

    // persistent owner state in registers
    float a_reg = (t < 4) ? a[r0 + t] : 0.f;
    float b_reg0 = 0.f, b_reg1 = 0.f;
    if (lane == 0) { b_reg0 = b[j0]; b_reg1 = b[j0 + 1]; }
    float u_reg = 0.f;
    float v_reg0 = 1.f, v_reg1 = 1.f;

    // ---- phase 0: u = mb/Ksum, v = 1 ----
    if (wid == 0) {
        float s = g_load(wsf + WS_KSUM_SLOTS + lane);
        s = wave_sum(s);
        if (lane == 0) sh0 = mb / (s + TINYX);
    }
    __syncthreads();
    u_reg = sh0;
    if (t < 4) g_store(wsf + WSN_U + r0 + t, u_reg);
    if (lane == 0) {
        g_store(wsf + WSN_V + j0, 1.f);
        g_store(wsf + WSN_V + j0 + 1, 1.f);
    }
    grid_bar(cnt, ++barcnt);

    // ---- main loop ----
    for (int it = 0; it <= NITER; ++it) {
        // ===== row pass: stage v (vec sc1), fold g, dot, row clip =====
        stage_v8(wsf + WSN_V, t, lv);
        {
            float gp = (it > 0 && t < 256) ? g_load(wsf + WSN_T + ((it - 1) & 1) * 256 + t)
                                           : 0.f;
            gp = wave_sum(gp);
            if (lane == 0) gred[wid] = gp;
        }
        __syncthreads();
        float g = 1.f;
        if (it > 0) {
            float ts = gred[0] + gred[1] + gred[2] + gred[3];
            g = mb / (ts + TINYX);
        }
        {
            int i = r0 + (wid >> 1);
            int dw0 = (wid & 1) << 10;
            const unsigned* Kr = (const unsigned*)K + ((size_t)i << 11);
            float s = 0.f;
#pragma unroll
            for (int p = 0; p < 16; ++p) {
                int dw = dw0 + (p << 6) + lane;
                unsigned kk = Kr[dw];
                float2 vv = *(const float2*)&lv[dw << 1];
                s = fmaf(__uint_as_float(kk << 16), vv.x, s);
                s = fmaf(__uint_as_float(kk & 0xffff0000u), vv.y, s);
            }
            s = wave_sum(s);
            if (lane == 0) red[wid] = s;
        }
        __syncthreads();
        if (t < 4) {
            float y = red[2 * t] + red[2 * t + 1];
            float ue = u_reg * g;
            float rr = ue * y;
            u_reg = ue * fminf(a_reg / (rr + TINYX), 1.f);
            g_store(wsf + WSN_U + r0 + t, u_reg);
        }
        grid_bar(cnt, ++barcnt);

        // ===== col pass: stage u (vec sc1), dot, col clip, t partial =====
        stage_u2(wsf + WSN_U, t, lu);
        __syncthreads();
#pragma unroll
        for (int c = 0; c < 2; ++c) {
            int j = j0 + c;
            const unsigned* Kc = (const unsigned*)KT + ((size_t)j << 9);
            float s = 0.f;
#pragma unroll
            for (int p = 0; p < 8; ++p) {
                int dw = (p << 6) + lane;
                unsigned kk = Kc[dw];
                float2 uu = *(const float2*)&lu[dw << 1];
                s = fmaf(__uint_as_float(kk << 16), uu.x, s);
                s = fmaf(__uint_as_float(kk & 0xffff0000u), uu.y, s);
            }
            s = wave_sum(s);
            if (lane == 0) {
                float vj = (c == 0) ? v_reg0 : v_reg1;
                float cc = vj * s;
                float bj = (c == 0) ? b_reg0 : b_reg1;
                float scv = fminf(bj / (cc + TINYX), 1.f);
                float vn = vj * scv;
                if (c == 0) v_reg0 = vn; else v_reg1 = vn;
                g_store(wsf + WSN_V + j, vn);
                float cw = cc * scv;
                cws[(wid << 1) + c] = cw;
                if (it == NITER) usage[j] = cw;
            }
        }
        __syncthreads();
        if (t == 0) {
            float ts = 0.f;
#pragma unroll
            for (int q = 0; q < 16; ++q) ts += cws[q];
            g_store(wsf + WSN_T + (it & 1) * 256 + bid, ts);
        }
        grid_bar(cnt, ++barcnt);
    }

    // ---- writeback: plan = K*u*v, score partial ----
    stage_u2(wsf + WSN_U, t, lu);
    stage_v8(wsf + WSN_V, t, lv);
    __syncthreads();
    float sc = 0.f;
    for (int r = 0; r < 4; ++r) {
        int i = r0 + r;
        float ui = lu[i];
        const unsigned* Kr = (const unsigned*)K + ((size_t)i << 11);
        float2* Pr = (float2*)(plan + ((size_t)i << 12));
#pragma unroll
        for (int q = 0; q < 4; ++q) {
            int dw = t + (q << 9);
            unsigned kk = Kr[dw];
            float k0 = __uint_as_float(kk << 16);
            float k1 = __uint_as_float(kk & 0xffff0000u);
            float2 vv = *(const float2*)&lv[dw << 1];
            float p0 = k0 * ui * vv.x;
            float p1 = k1 * ui * vv.y;
            Pr[dw] = make_float2(p0, p1);
            sc += p0 * __logf(k0) + p1 * __logf(k1);
        }
    }
    sc = wave_sum(sc);
    if (lane == 0) red[wid] = sc;
    __syncthreads();
    if (t == 0) {
        float st = 0.f;
#pragma unroll
        for (int q = 0; q < 8; ++q) st += red[q];
        g_store(wsf + WSN_SC + bid, st);
    }
    grid_bar(cnt, ++barcnt);

    // ---- epilogue by WG0 ----
    if (bid == 0) {
        float sp = 0.f, tp = 0.f;
        if (t < 256) {
            sp = g_load(wsf + WSN_SC + t);
            tp = g_load(wsf + WSN_T + (NITER & 1) * 256 + t);
        }
        sp = wave_sum(sp);
        tp = wave_sum(tp);
        if (lane == 0) { red[wid] = sp; red2[wid] = tp; }
        __syncthreads();
        if (t == 0) {
            float ssum = 0.f, tsum = 0.f;
#pragma unroll
            for (int q = 0; q < 8; ++q) { ssum += red[q]; tsum += red2[q]; }
            out[0] = EPSX * ssum;
            out[1 + (size_t)MM * NN] = tsum;
        }
    }
}

// ======================= f32 fallback (small ws) — round-1 proven =======================
__global__ void k_makeK_f32(float* costK, const float* cap, float* ws) {
    __shared__ float red[4];
    int t = threadIdx.x;
    float inv_mc = 1.f / (__uint_as_float(*(const unsigned*)&ws[WS_MAXCOST]) + TINYX);
    float inv_cap = 1.f / (ws[WS_MAXCAP] + TINYX);
    float lsum = 0.f;
    for (int s = 0; s < 4; s++) {
        size_t idx = (size_t)blockIdx.x * 1024 + s * 256 + t;
        int gc = (int)(idx & (NN - 1));
        float c = costK[idx] * inv_mc + STRENGTH * (1.f - cap[gc] * inv_cap);
        float kf = expf(-c * (1.f / EPSX));
        costK[idx] = kf;
        lsum += kf;
    }
    lsum = wave_sum(lsum);
    if ((t & 63) == 0) red[t >> 6] = lsum;
    __syncthreads();
    if (t == 0)
        atomicAdd(&ws[WS_KSUM_SLOTS + (blockIdx.x & 63)], red[0] + red[1] + red[2] + red[3]);
}

__global__ void k_init_uv(float* ws, const float* mbp) {
    __shared__ float s0s;
    int t = threadIdx.x;
    if (t < 64) {
        float s = ws[WS_KSUM_SLOTS + t];
        s = wave_sum(s);
        if (t == 0) s0s = mbp[0] / (s + TINYX);
    }
    __syncthreads();
    float s0 = s0s;
    for (int i = t; i < MM; i += 256) ws[WS_U + i] = s0;
    for (int j = t; j < NN; j += 256) ws[WS_V + j] = 1.f;
}

__global__ __launch_bounds__(256) void k_row_f32(const float* K, const float* a, const float* mbp,
                                                 float* ws, int iter) {
    __shared__ float red[4];
    int t = threadIdx.x, i = blockIdx.x;
    const float* Krow = K + (size_t)i * NN;
    const float* v = ws + WS_V;
    float s = 0.f;
    for (int p = 0; p < 16; p++) {
        int j = t + p * 256;
        s += Krow[j] * v[j];
    }
    s = wave_sum(s);
    if ((t & 63) == 0) red[t >> 6] = s;
    __syncthreads();
    if (blockIdx.x == 0 && t >= 64 && t < 128) ws[WS_T_SLOTS + (iter & 1) * 64 + t - 64] = 0.f;
    if (t < 64) {
        float y = red[0] + red[1] + red[2] + red[3];
        float g = 1.f;
        if (iter > 0) {
            float tp = ws[WS_T_SLOTS + ((iter - 1) & 1) * 64 + t];
            tp = wave_sum(tp);
            g = mbp[0] / (tp + TINYX);
        }
        if (t == 0) {
            float ue = ws[WS_U + i] * g;
            float r = ue * y;
            ws[WS_U + i] = ue * fminf(a[i] / (r + TINYX), 1.f);
        }
    }
}

__global__ __launch_bounds__(256) void k_col_f32(const float* K, const float* b, float* ws,
                                                 int iter, float* usage_out) {
    __shared__ float red[4];
    int t = threadIdx.x;
    int j = blockIdx.x * 256 + t;
    const float* u = ws + WS_U;
    float s = 0.f;
    for (int i = 0; i < MM; i++) s += K[(size_t)i * NN + j] * u[i];
    float vj = ws[WS_V + j];
    float c = vj * s;
    float sc = fminf(b[j] / (c + TINYX), 1.f);
    ws[WS_V + j] = vj * sc;
    float cw = c * sc;
    if (usage_out) usage_out[j] = cw;
    float bs = wave_sum(cw);
    if ((t & 63) == 0) red[t >> 6] = bs;
    __syncthreads();
    if (t == 0)
        atomicAdd(&ws[WS_T_SLOTS + (iter & 1) * 64 + (blockIdx.x & 63)],
                  red[0] + red[1] + red[2] + red[3]);
}

__global__ __launch_bounds__(256) void k_write_f32(float* K, float* ws) {
    __shared__ float red[4];
    int t = threadIdx.x;
    float sc = 0.f;
    for (int s = 0; s < 4; s++) {
        size_t idx = (size_t)blockIdx.x * 256 + (size_t)s * 1048576 + t;
        int i = (int)(idx >> 12), j = (int)(idx & (NN - 1));
        float kf = K[idx];
        float p = kf * ws[WS_U + i] * ws[WS_V + j];
        K[idx] = p;
        sc += p * __logf(kf);
    }
    sc = wave_sum(sc);
    if ((t & 63) == 0) red[t >> 6] = sc;
    __syncthreads();
    if (t == 0)
        atomicAdd(&ws[WS_SCORE_SLOTS + (blockIdx.x & 63)], red[0] + red[1] + red[2] + red[3]);
}

__global__ void k_epi(const float* ws, float* out) {
    int t = threadIdx.x;
    float s = ws[WS_SCORE_SLOTS + t];
    s = wave_sum(s);
    float tt = ws[WS_T_SLOTS + (NITER & 1) * 64 + t];
    tt = wave_sum(tt);
    if (t == 0) {
        out[0] = EPSX * s;
        out[1 + (size_t)MM * NN] = tt;
    }
}

extern "C" void kernel_launch(void* const* d_in, const int* in_sizes, int n_in,
                              void* d_out, int out_size, void* d_ws, size_t ws_size,
                              hipStream_t stream) {
    const float* U = (const float*)d_in[0];
    const float* V = (const float*)d_in[1];
    const float* a = (const float*)d_in[2];
    const float* b = (const float*)d_in[3];
    const float* mb = (const float*)d_in[4];
    float* out = (float*)d_out;
    float* ws = (float*)d_ws;
    float* plan = out + 1;
    float* usage = out + 2 + (size_t)MM * NN;

    bool fast = (ws_size >= FAST_NEED);
    ushortT* K = (ushortT*)((char*)d_ws + K_BYTE_OFF);
    ushortT* KT = K + (size_t)MM * NN;

    k_init<<<1, 256, 0, stream>>>(ws, b);
    k_norms<<<1280, 256, 0, stream>>>(U, V, ws);
    k_cost<<<1024, 256, 0, stream>>>(U, V, plan, ws);

    if (fast) {
        k_makeK<<<1024, 256, 0, stream>>>(plan, b, ws, K, KT);
        const ushortT* Kc = K;
        const ushortT* KTc = KT;
        void* kargs[] = {(void*)&Kc, (void*)&KTc, (void*)&a, (void*)&b,
                         (void*)&mb, (void*)&ws, (void*)&out};
        hipLaunchCooperativeKernel((const void*)k_loop, dim3(NWG), dim3(NTHR),
                                   kargs, 0, stream);
    } else {
        k_makeK_f32<<<4096, 256, 0, stream>>>(plan, b, ws);
        k_init_uv<<<1, 256, 0, stream>>>(ws, mb);
        for (int it = 0; it <= NITER; it++) {
            k_row_f32<<<MM, 256, 0, stream>>>(plan, a, mb, ws, it);
            k_col_f32<<<NN / 256, 256, 0, stream>>>(plan, b, ws, it, (it == NITER) ? usage : nullptr);
        }
        k_write_f32<<<4096, 256, 0, stream>>>(plan, ws);
        k_epi<<<1, 64, 0, stream>>>(ws, out);
    }
}